// Round 6
// baseline (363.899 us; speedup 1.0000x reference)
//
#include <hip/hip_runtime.h>
#include <cstdint>
#include <cstddef>

// Problem constants
#define NN    50000
#define EE    800000
#define ET    850000   /* EE + NN self-loops */
#define SLOPE 0.2f
#define MT    391      /* (NN+127)/128 gemm row-blocks */
#define EB    3322     /* (ET+255)/256 edge blocks */

typedef unsigned short ushortT;
typedef __attribute__((ext_vector_type(8))) short short8;
typedef __attribute__((ext_vector_type(4))) float floatx4;

__device__ __forceinline__ float lrelu(float x){ return x > 0.f ? x : SLOPE * x; }
__device__ __forceinline__ float eluf(float x){ return x > 0.f ? x : __expf(x) - 1.f; }
__device__ __forceinline__ ushortT f2b(float f){ unsigned u = __float_as_uint(f); u += 0x7fff + ((u >> 16) & 1); return (ushortT)(u >> 16); }
__device__ __forceinline__ float   b2f(ushortT b){ return __uint_as_float(((unsigned)b) << 16); }

__device__ __forceinline__ void edge_sd(const int* __restrict__ srcA, const int* __restrict__ dstA,
                                        int e, int& s, int& d)
{
    if (e < EE) { s = srcA[e]; d = dstA[e]; }
    else        { s = e - EE;  d = s; }
}

// ---------------------------------------------------------------------------
// GEMM body: C[M, NT*16](bf16) = A[M,256] @ BT[NT*16,256]^T
// + fused attention-logit epilogue. 128 rows/block, 4 waves.
// ---------------------------------------------------------------------------
template<bool A_F32, int NT, int HEADS>
__device__ __forceinline__ void gemm_body(const void* __restrict__ Aptr,
                                          const ushortT* __restrict__ BT,
                                          const float* __restrict__ attS,
                                          const float* __restrict__ attD,
                                          ushortT* __restrict__ C,
                                          float* __restrict__ asrc,
                                          float* __restrict__ adst,
                                          int M, int bId,
                                          ushortT* As, ushortT* Bs)
{
    constexpr int NCOL = NT * 16;
    const int tid  = threadIdx.x;
    const int wave = tid >> 6;
    const int lane = tid & 63;
    const int m16  = lane & 15;
    const int quad = lane >> 4;
    const int row0 = bId * 128;
    const int arow = tid >> 1;
    const int acol = (tid & 1) << 4;
    const long arowG = min(row0 + arow, M - 1);

    floatx4 acc[2][NT];
    #pragma unroll
    for (int i = 0; i < 2; ++i)
        #pragma unroll
        for (int j = 0; j < NT; ++j) acc[i][j] = (floatx4){0.f, 0.f, 0.f, 0.f};

    for (int k0 = 0; k0 < 256; k0 += 32) {
        ushortT a16[16];
        if (A_F32) {
            const float* A = (const float*)Aptr;
            #pragma unroll
            for (int q = 0; q < 4; ++q) {
                float4 f = *(const float4*)(A + arowG * 256 + k0 + acol + q * 4);
                a16[q*4+0] = f2b(f.x); a16[q*4+1] = f2b(f.y);
                a16[q*4+2] = f2b(f.z); a16[q*4+3] = f2b(f.w);
            }
        } else {
            const ushortT* A = (const ushortT*)Aptr;
            *(uint4*)(a16)     = *(const uint4*)(A + arowG * 256 + k0 + acol);
            *(uint4*)(a16 + 8) = *(const uint4*)(A + arowG * 256 + k0 + acol + 8);
        }
        uint4 bst[(NT == 16) ? 4 : 1];
        if (NT == 16) {
            const ushortT* bp = BT + (size_t)tid * 256 + k0;
            #pragma unroll
            for (int q = 0; q < 4; ++q) bst[q] = *(const uint4*)(bp + q * 8);
        } else {
            int brow = tid >> 2, bcol = (tid & 3) << 3;
            bst[0] = *(const uint4*)(BT + (size_t)brow * 256 + k0 + bcol);
        }

        __syncthreads();
        *(uint4*)(&As[arow * 40 + acol])     = *(uint4*)(a16);
        *(uint4*)(&As[arow * 40 + acol + 8]) = *(uint4*)(a16 + 8);
        if (NT == 16) {
            #pragma unroll
            for (int q = 0; q < 4; ++q) *(uint4*)(&Bs[tid * 40 + q * 8]) = bst[q];
        } else {
            int brow = tid >> 2, bcol = (tid & 3) << 3;
            *(uint4*)(&Bs[brow * 40 + bcol]) = bst[0];
        }
        __syncthreads();

        short8 af0 = *(const short8*)(&As[(wave * 32 + m16) * 40 + quad * 8]);
        short8 af1 = *(const short8*)(&As[(wave * 32 + 16 + m16) * 40 + quad * 8]);
        #pragma unroll
        for (int j = 0; j < NT; ++j) {
            short8 bf = *(const short8*)(&Bs[(j * 16 + m16) * 40 + quad * 8]);
            acc[0][j] = __builtin_amdgcn_mfma_f32_16x16x32_bf16(af0, bf, acc[0][j], 0, 0, 0);
            acc[1][j] = __builtin_amdgcn_mfma_f32_16x16x32_bf16(af1, bf, acc[1][j], 0, 0, 0);
        }
    }

    float attSv[NT], attDv[NT];
    #pragma unroll
    for (int j = 0; j < NT; ++j) {
        attSv[j] = attS[j * 16 + m16];
        attDv[j] = attD[j * 16 + m16];
    }

    #pragma unroll
    for (int i = 0; i < 2; ++i) {
        #pragma unroll
        for (int r = 0; r < 4; ++r) {
            int row = row0 + wave * 32 + i * 16 + quad * 4 + r;
            bool ok = row < M;
            if (ok) {
                #pragma unroll
                for (int j = 0; j < NT; ++j)
                    C[(size_t)row * NCOL + j * 16 + m16] = f2b(acc[i][j][r]);
            }
            float ds[HEADS], dd[HEADS];
            #pragma unroll
            for (int h = 0; h < HEADS; ++h) {
                float s = 0.f, d2 = 0.f;
                #pragma unroll
                for (int jj = 0; jj < 4; ++jj) {
                    int j = h * 4 + jj;
                    s  += acc[i][j][r] * attSv[j];
                    d2 += acc[i][j][r] * attDv[j];
                }
                #pragma unroll
                for (int off = 1; off < 16; off <<= 1) {
                    s  += __shfl_xor(s, off);
                    d2 += __shfl_xor(d2, off);
                }
                ds[h] = s; dd[h] = d2;
            }
            if (ok && m16 == 0) {
                if (HEADS == 4) {
                    *(float4*)(asrc + (size_t)row * 4) = make_float4(ds[0], ds[1], ds[2], ds[3]);
                    *(float4*)(adst + (size_t)row * 4) = make_float4(dd[0], dd[1], dd[2], dd[3]);
                } else {
                    asrc[row] = ds[0];
                    adst[row] = dd[0];
                }
            }
        }
    }
}

// ---------------------------------------------------------------------------
// Fused prep: blocks 0..255 cast weights; blocks 256.. histogram edge dst.
// (both parts low-VGPR/no-LDS -> safe heterogeneous fusion)
// ---------------------------------------------------------------------------
__global__ __launch_bounds__(256) void prep_k(const float* __restrict__ W1, const float* __restrict__ W2,
                                              ushortT* __restrict__ W1T, ushortT* __restrict__ W2T,
                                              const int* __restrict__ srcA, const int* __restrict__ dstA,
                                              int* __restrict__ counts)
{
    int t = threadIdx.x;
    if (blockIdx.x < 256) {
        int k = blockIdx.x;
        W1T[t * 256 + k] = f2b(W1[k * 256 + t]);
        if (t < 64) W2T[t * 256 + k] = f2b(W2[k * 64 + t]);
    } else {
        int e = (blockIdx.x - 256) * 256 + t;
        if (e >= ET) return;
        int s, d; edge_sd(srcA, dstA, e, s, d);
        atomicAdd(counts + d, 1);
    }
}

// ---------------------------------------------------------------------------
// Scan kernels (exclusive prefix sum of counts -> rowStart, cursor)
// ---------------------------------------------------------------------------
__global__ __launch_bounds__(256) void scan1_k(const int* __restrict__ counts,
                                               int* __restrict__ tmp, int* __restrict__ bsum)
{
    __shared__ int sm[256];
    int i = blockIdx.x * 256 + threadIdx.x;
    int v = (i < NN) ? counts[i] : 0;
    sm[threadIdx.x] = v;
    __syncthreads();
    #pragma unroll
    for (int off = 1; off < 256; off <<= 1) {
        int t = (threadIdx.x >= off) ? sm[threadIdx.x - off] : 0;
        __syncthreads();
        sm[threadIdx.x] += t;
        __syncthreads();
    }
    if (i < NN) tmp[i] = sm[threadIdx.x] - v;
    if (threadIdx.x == 255) bsum[blockIdx.x] = sm[255];
}

__global__ __launch_bounds__(256) void scan2_k(int* __restrict__ bsum, int nb)
{
    __shared__ int sm[256];
    int v = (threadIdx.x < nb) ? bsum[threadIdx.x] : 0;
    sm[threadIdx.x] = v;
    __syncthreads();
    #pragma unroll
    for (int off = 1; off < 256; off <<= 1) {
        int t = (threadIdx.x >= off) ? sm[threadIdx.x - off] : 0;
        __syncthreads();
        sm[threadIdx.x] += t;
        __syncthreads();
    }
    if (threadIdx.x < nb) bsum[threadIdx.x] = sm[threadIdx.x] - v;
}

__global__ __launch_bounds__(256) void scan3_k(const int* __restrict__ tmp, const int* __restrict__ bsum,
                                               int* __restrict__ rowStart, int* __restrict__ cursor)
{
    int i = blockIdx.x * 256 + threadIdx.x;
    if (i >= NN) return;
    int v = tmp[i] + bsum[blockIdx.x];
    rowStart[i] = v;
    cursor[i]   = v;
}

// Scatter standalone: 8 VGPR / 0 LDS -> full occupancy for latency hiding.
__global__ __launch_bounds__(256) void scatter_k(const int* __restrict__ srcA, const int* __restrict__ dstA,
                                                 int* __restrict__ cursor, int* __restrict__ esorted)
{
    int e = blockIdx.x * 256 + threadIdx.x;
    if (e >= ET) return;
    int s, d; edge_sd(srcA, dstA, e, s, d);
    int pos = atomicAdd(cursor + d, 1);
    esorted[pos] = s;
}

// Layer-1 GEMM standalone (compute-dense; 30KB LDS / high VGPR is fine here)
__global__ __launch_bounds__(256) void gemm1_k(const float* __restrict__ x,
                                               const ushortT* __restrict__ W1T,
                                               const float* __restrict__ attS,
                                               const float* __restrict__ attD,
                                               ushortT* __restrict__ h1b,
                                               float* __restrict__ asrc,
                                               float* __restrict__ adst)
{
    __shared__ ushortT As[128 * 40];
    __shared__ ushortT Bs[256 * 40];
    gemm_body<true, 16, 4>(x, W1T, attS, attD, h1b, asrc, adst, NN, blockIdx.x, As, Bs);
}

// Layer-2 GEMM standalone
__global__ __launch_bounds__(256) void gemm2_k(const ushortT* __restrict__ a2b,
                                               const ushortT* __restrict__ W2T,
                                               const float* __restrict__ attS,
                                               const float* __restrict__ attD,
                                               ushortT* __restrict__ t2b,
                                               float* __restrict__ asrc,
                                               float* __restrict__ adst)
{
    __shared__ ushortT As[128 * 40];
    __shared__ ushortT Bs[64 * 40];
    gemm_body<false, 4, 1>(a2b, W2T, attS, attD, t2b, asrc, adst, NN, blockIdx.x, As, Bs);
}

// ---------------------------------------------------------------------------
// agg1: single chunked pass. Lane=edge computes p (4 heads) ONCE, stashes
// (p4, src) in wave-local LDS; all lanes then gather h1b rows weighted by the
// LDS-broadcast p. No max-subtraction needed (logits O(7), f32 exp safe).
// One wave per node. Epilogue: *1/den, +b1, ELU, bf16 store.
// ---------------------------------------------------------------------------
__global__ __launch_bounds__(256) void agg1_k(const int* __restrict__ esorted,
                                              const int* __restrict__ rowStart,
                                              const int* __restrict__ counts,
                                              const ushortT* __restrict__ h1b,
                                              const float* __restrict__ asrc,
                                              const float* __restrict__ adst,
                                              const float* __restrict__ b1,
                                              ushortT* __restrict__ a2b)
{
    __shared__ float pbuf[4][64][4];
    __shared__ int   sbuf[4][64];
    int w = threadIdx.x >> 6;
    int lane = threadIdx.x & 63;
    int n = blockIdx.x * 4 + w;
    if (n >= NN) return;
    int start = rowStart[n], deg = counts[n];
    float4 adv = *(const float4*)(adst + (size_t)n * 4);
    int h = lane >> 4;
    int c4 = lane * 4;

    float4 ssv = make_float4(0.f, 0.f, 0.f, 0.f);
    float4 ac0 = make_float4(0.f,0.f,0.f,0.f);
    float4 ac1 = make_float4(0.f,0.f,0.f,0.f);
    float4 ac2 = make_float4(0.f,0.f,0.f,0.f);
    float4 ac3 = make_float4(0.f,0.f,0.f,0.f);

    for (int base = 0; base < deg; base += 64) {
        int cl = min(64, deg - base);
        int i = base + lane;
        if (i < deg) {
            int s = esorted[start + i];
            float4 a = *(const float4*)(asrc + (size_t)s * 4);
            float4 pv;
            pv.x = __expf(lrelu(a.x + adv.x));
            pv.y = __expf(lrelu(a.y + adv.y));
            pv.z = __expf(lrelu(a.z + adv.z));
            pv.w = __expf(lrelu(a.w + adv.w));
            ssv.x += pv.x; ssv.y += pv.y; ssv.z += pv.z; ssv.w += pv.w;
            *(float4*)(&pbuf[w][lane][0]) = pv;
            sbuf[w][lane] = s;
        }
        __builtin_amdgcn_wave_barrier();   // intra-wave LDS write->read ordering
        int j = 0;
        for (; j + 3 < cl; j += 4) {
            int s0 = sbuf[w][j], s1 = sbuf[w][j+1], s2 = sbuf[w][j+2], s3 = sbuf[w][j+3];
            float p0 = pbuf[w][j][h], p1 = pbuf[w][j+1][h], p2 = pbuf[w][j+2][h], p3 = pbuf[w][j+3][h];
            ushort4 h0 = *(const ushort4*)(h1b + (size_t)s0 * 256 + c4);
            ushort4 h1 = *(const ushort4*)(h1b + (size_t)s1 * 256 + c4);
            ushort4 h2 = *(const ushort4*)(h1b + (size_t)s2 * 256 + c4);
            ushort4 h3 = *(const ushort4*)(h1b + (size_t)s3 * 256 + c4);
            ac0.x += b2f(h0.x) * p0; ac0.y += b2f(h0.y) * p0; ac0.z += b2f(h0.z) * p0; ac0.w += b2f(h0.w) * p0;
            ac1.x += b2f(h1.x) * p1; ac1.y += b2f(h1.y) * p1; ac1.z += b2f(h1.z) * p1; ac1.w += b2f(h1.w) * p1;
            ac2.x += b2f(h2.x) * p2; ac2.y += b2f(h2.y) * p2; ac2.z += b2f(h2.z) * p2; ac2.w += b2f(h2.w) * p2;
            ac3.x += b2f(h3.x) * p3; ac3.y += b2f(h3.y) * p3; ac3.z += b2f(h3.z) * p3; ac3.w += b2f(h3.w) * p3;
        }
        for (; j < cl; ++j) {
            int s0 = sbuf[w][j];
            float p0 = pbuf[w][j][h];
            ushort4 h0 = *(const ushort4*)(h1b + (size_t)s0 * 256 + c4);
            ac0.x += b2f(h0.x) * p0; ac0.y += b2f(h0.y) * p0; ac0.z += b2f(h0.z) * p0; ac0.w += b2f(h0.w) * p0;
        }
        __builtin_amdgcn_wave_barrier();   // reads done before next chunk's writes
    }

    #pragma unroll
    for (int off = 1; off < 64; off <<= 1) {
        ssv.x += __shfl_xor(ssv.x, off); ssv.y += __shfl_xor(ssv.y, off);
        ssv.z += __shfl_xor(ssv.z, off); ssv.w += __shfl_xor(ssv.w, off);
    }
    float ssh = (h < 2) ? (h == 0 ? ssv.x : ssv.y) : (h == 2 ? ssv.z : ssv.w);
    float rdh = 1.f / ssh;

    float4 bv = *(const float4*)(b1 + c4);
    ushort4 o;
    o.x = f2b(eluf((ac0.x + ac1.x + ac2.x + ac3.x) * rdh + bv.x));
    o.y = f2b(eluf((ac0.y + ac1.y + ac2.y + ac3.y) * rdh + bv.y));
    o.z = f2b(eluf((ac0.z + ac1.z + ac2.z + ac3.z) * rdh + bv.z));
    o.w = f2b(eluf((ac0.w + ac1.w + ac2.w + ac3.w) * rdh + bv.w));
    *(ushort4*)(a2b + (size_t)n * 256 + c4) = o;
}

// ---------------------------------------------------------------------------
// agg2: same chunked-LDS structure, 1 head + bias + log_softmax.
// ---------------------------------------------------------------------------
__global__ __launch_bounds__(256) void agg2_k(const int* __restrict__ esorted,
                                              const int* __restrict__ rowStart,
                                              const int* __restrict__ counts,
                                              const ushortT* __restrict__ t2b,
                                              const float* __restrict__ asrc,
                                              const float* __restrict__ adst,
                                              const float* __restrict__ b2,
                                              float* __restrict__ out)
{
    __shared__ float pbuf[4][64];
    __shared__ int   sbuf[4][64];
    int w = threadIdx.x >> 6;
    int lane = threadIdx.x & 63;
    int n = blockIdx.x * 4 + w;
    if (n >= NN) return;
    int start = rowStart[n], deg = counts[n];
    float adv = adst[n];

    float ss = 0.f;
    float a0 = 0.f, a1 = 0.f, a2 = 0.f, a3 = 0.f;

    for (int base = 0; base < deg; base += 64) {
        int cl = min(64, deg - base);
        int i = base + lane;
        if (i < deg) {
            int s = esorted[start + i];
            float p = __expf(lrelu(asrc[s] + adv));
            ss += p;
            pbuf[w][lane] = p;
            sbuf[w][lane] = s;
        }
        __builtin_amdgcn_wave_barrier();
        int j = 0;
        for (; j + 3 < cl; j += 4) {
            int s0 = sbuf[w][j], s1 = sbuf[w][j+1], s2 = sbuf[w][j+2], s3 = sbuf[w][j+3];
            float p0 = pbuf[w][j], p1 = pbuf[w][j+1], p2 = pbuf[w][j+2], p3 = pbuf[w][j+3];
            a0 += b2f(t2b[(size_t)s0 * 64 + lane]) * p0;
            a1 += b2f(t2b[(size_t)s1 * 64 + lane]) * p1;
            a2 += b2f(t2b[(size_t)s2 * 64 + lane]) * p2;
            a3 += b2f(t2b[(size_t)s3 * 64 + lane]) * p3;
        }
        for (; j < cl; ++j) {
            a0 += b2f(t2b[(size_t)sbuf[w][j] * 64 + lane]) * pbuf[w][j];
        }
        __builtin_amdgcn_wave_barrier();
    }

    #pragma unroll
    for (int off = 1; off < 64; off <<= 1) ss += __shfl_xor(ss, off);
    float v = (a0 + a1 + a2 + a3) / ss + b2[lane];

    float m2 = v;
    #pragma unroll
    for (int off = 32; off; off >>= 1) m2 = fmaxf(m2, __shfl_xor(m2, off));
    float ex = __expf(v - m2);
    float sm = ex;
    #pragma unroll
    for (int off = 32; off; off >>= 1) sm += __shfl_xor(sm, off);
    out[(size_t)n * 64 + lane] = v - m2 - __logf(sm);
}

// ---------------------------------------------------------------------------
extern "C" void kernel_launch(void* const* d_in, const int* in_sizes, int n_in,
                              void* d_out, int out_size, void* d_ws, size_t ws_size,
                              hipStream_t stream)
{
    const float* x   = (const float*)d_in[0];
    const int*   adj = (const int*)  d_in[1];
    const float* W1  = (const float*)d_in[2];
    const float* as1 = (const float*)d_in[3];
    const float* ad1 = (const float*)d_in[4];
    const float* b1  = (const float*)d_in[5];
    const float* W2  = (const float*)d_in[6];
    const float* as2 = (const float*)d_in[7];
    const float* ad2 = (const float*)d_in[8];
    const float* b2  = (const float*)d_in[9];
    float* out = (float*)d_out;

    const size_t szH1b = (size_t)NN * 256 * 2;   // 25.6 MB
    const size_t szT2b = (size_t)NN * 64 * 2;    // 6.4 MB
    const size_t szA4  = (size_t)NN * 4 * 4;     // 0.8 MB
    const size_t szA1  = (size_t)NN * 4;         // 0.2 MB
    const size_t szE   = (size_t)ET * 4;         // 3.4 MB

    char* p = (char*)d_ws;
    ushortT* h1b  = (ushortT*)p; p += szH1b;
    ushortT* a2b  = (ushortT*)p; p += szH1b;
    ushortT* t2b  = (ushortT*)p; p += szT2b;
    ushortT* W1T  = (ushortT*)p; p += 256 * 256 * 2;
    ushortT* W2T  = (ushortT*)p; p += 64 * 256 * 2;
    float* asrc1  = (float*)p; p += szA4;
    float* adst1  = (float*)p; p += szA4;
    float* asrc2  = (float*)p; p += szA1;
    float* adst2  = (float*)p; p += szA1;
    int* esorted  = (int*)p; p += szE;
    int* tmp      = (int*)p; p += szA1;
    int* rowStart = (int*)p; p += szA1;
    int* cursor   = (int*)p; p += szA1;
    int* counts   = (int*)p; p += szA1;
    int* bsum     = (int*)p; p += 4096;

    hipMemsetAsync(counts, 0, szA1, stream);

    const int nb  = (NN + 255) / 256;   // 196
    const int nwb = (NN + 3) / 4;       // 12500

    // castW (blocks 0..255) + hist (blocks 256..)
    prep_k<<<256 + EB, 256, 0, stream>>>(W1, W2, W1T, W2T, adj, adj + EE, counts);
    scan1_k<<<nb, 256, 0, stream>>>(counts, tmp, bsum);
    scan2_k<<<1,  256, 0, stream>>>(bsum, nb);
    scan3_k<<<nb, 256, 0, stream>>>(tmp, bsum, rowStart, cursor);
    scatter_k<<<EB, 256, 0, stream>>>(adj, adj + EE, cursor, esorted);

    // Layer 1
    gemm1_k<<<MT, 256, 0, stream>>>(x, W1T, as1, ad1, h1b, asrc1, adst1);
    agg1_k<<<nwb, 256, 0, stream>>>(esorted, rowStart, counts, h1b, asrc1, adst1, b1, a2b);

    // Layer 2
    gemm2_k<<<MT, 256, 0, stream>>>(a2b, W2T, as2, ad2, t2b, asrc2, adst2);
    agg2_k<<<nwb, 256, 0, stream>>>(esorted, rowStart, counts, t2b, asrc2, adst2, b2, out);
}

// Round 7
// 346.836 us; speedup vs baseline: 1.0492x; 1.0492x over previous
//
#include <hip/hip_runtime.h>
#include <cstdint>
#include <cstddef>

// Problem constants
#define NN    50000
#define EE    800000
#define ET    850000   /* EE + NN self-loops */
#define SLOPE 0.2f
#define MT    391      /* (NN+127)/128 gemm row-blocks */
#define EB    3322     /* (ET+255)/256 edge blocks */
#define SCB   831      /* (ET+1023)/1024 scatter blocks (4 edges/thread) */
#define XB    6250     /* castX blocks: 6250*2048 = 12.8M elems */

typedef unsigned short ushortT;
typedef __attribute__((ext_vector_type(8))) short short8;
typedef __attribute__((ext_vector_type(4))) float floatx4;

__device__ __forceinline__ float lrelu(float x){ return x > 0.f ? x : SLOPE * x; }
__device__ __forceinline__ float eluf(float x){ return x > 0.f ? x : __expf(x) - 1.f; }
__device__ __forceinline__ ushortT f2b(float f){ unsigned u = __float_as_uint(f); u += 0x7fff + ((u >> 16) & 1); return (ushortT)(u >> 16); }
__device__ __forceinline__ float   b2f(ushortT b){ return __uint_as_float(((unsigned)b) << 16); }

__device__ __forceinline__ void edge_sd(const int* __restrict__ srcA, const int* __restrict__ dstA,
                                        int e, int& s, int& d)
{
    if (e < EE) { s = srcA[e]; d = dstA[e]; }
    else        { s = e - EE;  d = s; }
}

// ---------------------------------------------------------------------------
// GEMM body: C[M, NT*16](bf16) = A[M,256](bf16) @ BT[NT*16,256]^T
// + fused attention-logit epilogue. 128 rows/block, 4 waves.
// ---------------------------------------------------------------------------
template<int NT, int HEADS>
__device__ __forceinline__ void gemm_body(const ushortT* __restrict__ A,
                                          const ushortT* __restrict__ BT,
                                          const float* __restrict__ attS,
                                          const float* __restrict__ attD,
                                          ushortT* __restrict__ C,
                                          float* __restrict__ asrc,
                                          float* __restrict__ adst,
                                          int M, int bId,
                                          ushortT* As, ushortT* Bs)
{
    constexpr int NCOL = NT * 16;
    const int tid  = threadIdx.x;
    const int wave = tid >> 6;
    const int lane = tid & 63;
    const int m16  = lane & 15;
    const int quad = lane >> 4;
    const int row0 = bId * 128;
    const int arow = tid >> 1;
    const int acol = (tid & 1) << 4;
    const long arowG = min(row0 + arow, M - 1);

    floatx4 acc[2][NT];
    #pragma unroll
    for (int i = 0; i < 2; ++i)
        #pragma unroll
        for (int j = 0; j < NT; ++j) acc[i][j] = (floatx4){0.f, 0.f, 0.f, 0.f};

    for (int k0 = 0; k0 < 256; k0 += 32) {
        uint4 a0 = *(const uint4*)(A + arowG * 256 + k0 + acol);
        uint4 a1 = *(const uint4*)(A + arowG * 256 + k0 + acol + 8);
        uint4 bst[(NT == 16) ? 4 : 1];
        if (NT == 16) {
            const ushortT* bp = BT + (size_t)tid * 256 + k0;
            #pragma unroll
            for (int q = 0; q < 4; ++q) bst[q] = *(const uint4*)(bp + q * 8);
        } else {
            int brow = tid >> 2, bcol = (tid & 3) << 3;
            bst[0] = *(const uint4*)(BT + (size_t)brow * 256 + k0 + bcol);
        }

        __syncthreads();
        *(uint4*)(&As[arow * 40 + acol])     = a0;
        *(uint4*)(&As[arow * 40 + acol + 8]) = a1;
        if (NT == 16) {
            #pragma unroll
            for (int q = 0; q < 4; ++q) *(uint4*)(&Bs[tid * 40 + q * 8]) = bst[q];
        } else {
            int brow = tid >> 2, bcol = (tid & 3) << 3;
            *(uint4*)(&Bs[brow * 40 + bcol]) = bst[0];
        }
        __syncthreads();

        short8 af0 = *(const short8*)(&As[(wave * 32 + m16) * 40 + quad * 8]);
        short8 af1 = *(const short8*)(&As[(wave * 32 + 16 + m16) * 40 + quad * 8]);
        #pragma unroll
        for (int j = 0; j < NT; ++j) {
            short8 bf = *(const short8*)(&Bs[(j * 16 + m16) * 40 + quad * 8]);
            acc[0][j] = __builtin_amdgcn_mfma_f32_16x16x32_bf16(af0, bf, acc[0][j], 0, 0, 0);
            acc[1][j] = __builtin_amdgcn_mfma_f32_16x16x32_bf16(af1, bf, acc[1][j], 0, 0, 0);
        }
    }

    float attSv[NT], attDv[NT];
    #pragma unroll
    for (int j = 0; j < NT; ++j) {
        attSv[j] = attS[j * 16 + m16];
        attDv[j] = attD[j * 16 + m16];
    }

    #pragma unroll
    for (int i = 0; i < 2; ++i) {
        #pragma unroll
        for (int r = 0; r < 4; ++r) {
            int row = row0 + wave * 32 + i * 16 + quad * 4 + r;
            bool ok = row < M;
            if (ok) {
                #pragma unroll
                for (int j = 0; j < NT; ++j)
                    C[(size_t)row * NCOL + j * 16 + m16] = f2b(acc[i][j][r]);
            }
            float ds[HEADS], dd[HEADS];
            #pragma unroll
            for (int h = 0; h < HEADS; ++h) {
                float s = 0.f, d2 = 0.f;
                #pragma unroll
                for (int jj = 0; jj < 4; ++jj) {
                    int j = h * 4 + jj;
                    s  += acc[i][j][r] * attSv[j];
                    d2 += acc[i][j][r] * attDv[j];
                }
                #pragma unroll
                for (int off = 1; off < 16; off <<= 1) {
                    s  += __shfl_xor(s, off);
                    d2 += __shfl_xor(d2, off);
                }
                ds[h] = s; dd[h] = d2;
            }
            if (ok && m16 == 0) {
                if (HEADS == 4) {
                    *(float4*)(asrc + (size_t)row * 4) = make_float4(ds[0], ds[1], ds[2], ds[3]);
                    *(float4*)(adst + (size_t)row * 4) = make_float4(dd[0], dd[1], dd[2], dd[3]);
                } else {
                    asrc[row] = ds[0];
                    adst[row] = dd[0];
                }
            }
        }
    }
}

// ---------------------------------------------------------------------------
// Fused prep: blocks [0,256) cast weights; [256,256+XB) cast x -> bf16;
// [256+XB, ...) histogram edge dst. All parts low-VGPR/no-LDS -> safe fusion.
// ---------------------------------------------------------------------------
__global__ __launch_bounds__(256) void prep_k(const float* __restrict__ W1, const float* __restrict__ W2,
                                              const float* __restrict__ x,
                                              ushortT* __restrict__ W1T, ushortT* __restrict__ W2T,
                                              ushortT* __restrict__ xb,
                                              const int* __restrict__ srcA, const int* __restrict__ dstA,
                                              int* __restrict__ counts)
{
    int t = threadIdx.x;
    int b = blockIdx.x;
    if (b < 256) {
        W1T[t * 256 + b] = f2b(W1[b * 256 + t]);
        if (t < 64) W2T[t * 256 + b] = f2b(W2[b * 64 + t]);
    } else if (b < 256 + XB) {
        size_t idx = (size_t)(b - 256) * 2048 + t * 8;
        float4 f0 = *(const float4*)(x + idx);
        float4 f1 = *(const float4*)(x + idx + 4);
        ushortT o[8];
        o[0]=f2b(f0.x); o[1]=f2b(f0.y); o[2]=f2b(f0.z); o[3]=f2b(f0.w);
        o[4]=f2b(f1.x); o[5]=f2b(f1.y); o[6]=f2b(f1.z); o[7]=f2b(f1.w);
        *(uint4*)(xb + idx) = *(uint4*)o;
    } else {
        int e = (b - 256 - XB) * 256 + t;
        if (e >= ET) return;
        int s, d; edge_sd(srcA, dstA, e, s, d);
        atomicAdd(counts + d, 1);
    }
}

// ---------------------------------------------------------------------------
// scan1: per-256-block inclusive scan -> exclusive tmp + block sums
// ---------------------------------------------------------------------------
__global__ __launch_bounds__(256) void scan1_k(const int* __restrict__ counts,
                                               int* __restrict__ tmp, int* __restrict__ bsum)
{
    __shared__ int sm[256];
    int i = blockIdx.x * 256 + threadIdx.x;
    int v = (i < NN) ? counts[i] : 0;
    sm[threadIdx.x] = v;
    __syncthreads();
    #pragma unroll
    for (int off = 1; off < 256; off <<= 1) {
        int t = (threadIdx.x >= off) ? sm[threadIdx.x - off] : 0;
        __syncthreads();
        sm[threadIdx.x] += t;
        __syncthreads();
    }
    if (i < NN) tmp[i] = sm[threadIdx.x] - v;
    if (threadIdx.x == 255) bsum[blockIdx.x] = sm[255];
}

// scan23: block b adds sum(bsum[0..b)) to tmp -> rowStart, cursor. (196 <= 256)
__global__ __launch_bounds__(256) void scan23_k(const int* __restrict__ tmp, const int* __restrict__ bsum,
                                                int* __restrict__ rowStart, int* __restrict__ cursor)
{
    __shared__ int sm[4];
    int t = threadIdx.x;
    int v = (t < blockIdx.x) ? bsum[t] : 0;
    #pragma unroll
    for (int off = 32; off; off >>= 1) v += __shfl_xor(v, off);
    if ((t & 63) == 0) sm[t >> 6] = v;
    __syncthreads();
    int base = sm[0] + sm[1] + sm[2] + sm[3];
    int i = blockIdx.x * 256 + t;
    if (i < NN) {
        int r = tmp[i] + base;
        rowStart[i] = r;
        cursor[i]   = r;
    }
}

// ---------------------------------------------------------------------------
// Fused: blocks [0,SCB) scatter edges (4 edges/thread, 4 outstanding atomics);
// blocks [SCB, SCB+MT) layer-1 GEMM (+alpha epilogue). Intra-dispatch overlap
// of the latency-bound scatter with the compute-bound GEMM (R4 vs R5 A/B:
// fusion is worth ~28us on this serialized stream).
// ---------------------------------------------------------------------------
__global__ __launch_bounds__(256) void gemmscatter_k(const ushortT* __restrict__ xb,
                                                     const ushortT* __restrict__ W1T,
                                                     const float* __restrict__ attS,
                                                     const float* __restrict__ attD,
                                                     ushortT* __restrict__ h1b,
                                                     float* __restrict__ asrc,
                                                     float* __restrict__ adst,
                                                     const int* __restrict__ srcA,
                                                     const int* __restrict__ dstA,
                                                     int* __restrict__ cursor,
                                                     int* __restrict__ esorted)
{
    __shared__ ushortT As[128 * 40];
    __shared__ ushortT Bs[256 * 40];
    if (blockIdx.x < SCB) {
        int base = blockIdx.x * 1024 + threadIdx.x;
        #pragma unroll
        for (int k = 0; k < 4; ++k) {
            int e = base + k * 256;
            if (e < ET) {
                int s, d; edge_sd(srcA, dstA, e, s, d);
                int pos = atomicAdd(cursor + d, 1);
                esorted[pos] = s;
            }
        }
    } else {
        gemm_body<16, 4>(xb, W1T, attS, attD, h1b, asrc, adst, NN, blockIdx.x - SCB, As, Bs);
    }
}

// Layer-2 GEMM standalone
__global__ __launch_bounds__(256) void gemm2_k(const ushortT* __restrict__ a2b,
                                               const ushortT* __restrict__ W2T,
                                               const float* __restrict__ attS,
                                               const float* __restrict__ attD,
                                               ushortT* __restrict__ t2b,
                                               float* __restrict__ asrc,
                                               float* __restrict__ adst)
{
    __shared__ ushortT As[128 * 40];
    __shared__ ushortT Bs[64 * 40];
    gemm_body<4, 1>(a2b, W2T, attS, attD, t2b, asrc, adst, NN, blockIdx.x, As, Bs);
}

// ---------------------------------------------------------------------------
// agg1: chunked pass. Lane=edge computes p (4 heads) once into wave-local LDS;
// all lanes gather h1b rows weighted by LDS-broadcast p. Phase B unroll 8.
// ---------------------------------------------------------------------------
__global__ __launch_bounds__(256) void agg1_k(const int* __restrict__ esorted,
                                              const int* __restrict__ rowStart,
                                              const int* __restrict__ counts,
                                              const ushortT* __restrict__ h1b,
                                              const float* __restrict__ asrc,
                                              const float* __restrict__ adst,
                                              const float* __restrict__ b1,
                                              ushortT* __restrict__ a2b)
{
    __shared__ float pbuf[4][64][4];
    __shared__ int   sbuf[4][64];
    int w = threadIdx.x >> 6;
    int lane = threadIdx.x & 63;
    int n = blockIdx.x * 4 + w;
    if (n >= NN) return;
    int start = rowStart[n], deg = counts[n];
    float4 adv = *(const float4*)(adst + (size_t)n * 4);
    int h = lane >> 4;
    int c4 = lane * 4;

    float4 ssv = make_float4(0.f, 0.f, 0.f, 0.f);
    float4 ac0 = make_float4(0.f,0.f,0.f,0.f);
    float4 ac1 = make_float4(0.f,0.f,0.f,0.f);
    float4 ac2 = make_float4(0.f,0.f,0.f,0.f);
    float4 ac3 = make_float4(0.f,0.f,0.f,0.f);

    for (int base = 0; base < deg; base += 64) {
        int cl = min(64, deg - base);
        int i = base + lane;
        if (i < deg) {
            int s = esorted[start + i];
            float4 a = *(const float4*)(asrc + (size_t)s * 4);
            float4 pv;
            pv.x = __expf(lrelu(a.x + adv.x));
            pv.y = __expf(lrelu(a.y + adv.y));
            pv.z = __expf(lrelu(a.z + adv.z));
            pv.w = __expf(lrelu(a.w + adv.w));
            ssv.x += pv.x; ssv.y += pv.y; ssv.z += pv.z; ssv.w += pv.w;
            *(float4*)(&pbuf[w][lane][0]) = pv;
            sbuf[w][lane] = s;
        }
        __builtin_amdgcn_wave_barrier();   // intra-wave LDS write->read ordering
        int j = 0;
        for (; j + 7 < cl; j += 8) {
            float4 hv[8]; float pp[8];
            #pragma unroll
            for (int q = 0; q < 8; ++q) {
                int sq = sbuf[w][j + q];
                pp[q] = pbuf[w][j + q][h];
                ushort4 hq = *(const ushort4*)(h1b + (size_t)sq * 256 + c4);
                hv[q] = make_float4(b2f(hq.x), b2f(hq.y), b2f(hq.z), b2f(hq.w));
            }
            #pragma unroll
            for (int q = 0; q < 8; ++q) {
                float4* ac = (q & 3) == 0 ? &ac0 : (q & 3) == 1 ? &ac1 : (q & 3) == 2 ? &ac2 : &ac3;
                ac->x += hv[q].x * pp[q]; ac->y += hv[q].y * pp[q];
                ac->z += hv[q].z * pp[q]; ac->w += hv[q].w * pp[q];
            }
        }
        for (; j < cl; ++j) {
            int s0 = sbuf[w][j];
            float p0 = pbuf[w][j][h];
            ushort4 h0 = *(const ushort4*)(h1b + (size_t)s0 * 256 + c4);
            ac0.x += b2f(h0.x) * p0; ac0.y += b2f(h0.y) * p0; ac0.z += b2f(h0.z) * p0; ac0.w += b2f(h0.w) * p0;
        }
        __builtin_amdgcn_wave_barrier();   // reads done before next chunk's writes
    }

    #pragma unroll
    for (int off = 1; off < 64; off <<= 1) {
        ssv.x += __shfl_xor(ssv.x, off); ssv.y += __shfl_xor(ssv.y, off);
        ssv.z += __shfl_xor(ssv.z, off); ssv.w += __shfl_xor(ssv.w, off);
    }
    float ssh = (h < 2) ? (h == 0 ? ssv.x : ssv.y) : (h == 2 ? ssv.z : ssv.w);
    float rdh = 1.f / ssh;

    float4 bv = *(const float4*)(b1 + c4);
    ushort4 o;
    o.x = f2b(eluf((ac0.x + ac1.x + ac2.x + ac3.x) * rdh + bv.x));
    o.y = f2b(eluf((ac0.y + ac1.y + ac2.y + ac3.y) * rdh + bv.y));
    o.z = f2b(eluf((ac0.z + ac1.z + ac2.z + ac3.z) * rdh + bv.z));
    o.w = f2b(eluf((ac0.w + ac1.w + ac2.w + ac3.w) * rdh + bv.w));
    *(ushort4*)(a2b + (size_t)n * 256 + c4) = o;
}

// ---------------------------------------------------------------------------
// agg2: same chunked-LDS structure, 1 head + bias + log_softmax. Unroll 8.
// ---------------------------------------------------------------------------
__global__ __launch_bounds__(256) void agg2_k(const int* __restrict__ esorted,
                                              const int* __restrict__ rowStart,
                                              const int* __restrict__ counts,
                                              const ushortT* __restrict__ t2b,
                                              const float* __restrict__ asrc,
                                              const float* __restrict__ adst,
                                              const float* __restrict__ b2,
                                              float* __restrict__ out)
{
    __shared__ float pbuf[4][64];
    __shared__ int   sbuf[4][64];
    int w = threadIdx.x >> 6;
    int lane = threadIdx.x & 63;
    int n = blockIdx.x * 4 + w;
    if (n >= NN) return;
    int start = rowStart[n], deg = counts[n];
    float adv = adst[n];

    float ss = 0.f;
    float a0 = 0.f, a1 = 0.f, a2 = 0.f, a3 = 0.f;

    for (int base = 0; base < deg; base += 64) {
        int cl = min(64, deg - base);
        int i = base + lane;
        if (i < deg) {
            int s = esorted[start + i];
            float p = __expf(lrelu(asrc[s] + adv));
            ss += p;
            pbuf[w][lane] = p;
            sbuf[w][lane] = s;
        }
        __builtin_amdgcn_wave_barrier();
        int j = 0;
        for (; j + 7 < cl; j += 8) {
            float tv[8]; float pp[8];
            #pragma unroll
            for (int q = 0; q < 8; ++q) {
                int sq = sbuf[w][j + q];
                pp[q] = pbuf[w][j + q];
                tv[q] = b2f(t2b[(size_t)sq * 64 + lane]);
            }
            #pragma unroll
            for (int q = 0; q < 8; ++q) {
                float* ac = (q & 3) == 0 ? &a0 : (q & 3) == 1 ? &a1 : (q & 3) == 2 ? &a2 : &a3;
                *ac += tv[q] * pp[q];
            }
        }
        for (; j < cl; ++j) {
            a0 += b2f(t2b[(size_t)sbuf[w][j] * 64 + lane]) * pbuf[w][j];
        }
        __builtin_amdgcn_wave_barrier();
    }

    #pragma unroll
    for (int off = 1; off < 64; off <<= 1) ss += __shfl_xor(ss, off);
    float v = (a0 + a1 + a2 + a3) / ss + b2[lane];

    float m2 = v;
    #pragma unroll
    for (int off = 32; off; off >>= 1) m2 = fmaxf(m2, __shfl_xor(m2, off));
    float ex = __expf(v - m2);
    float sm = ex;
    #pragma unroll
    for (int off = 32; off; off >>= 1) sm += __shfl_xor(sm, off);
    out[(size_t)n * 64 + lane] = v - m2 - __logf(sm);
}

// ---------------------------------------------------------------------------
extern "C" void kernel_launch(void* const* d_in, const int* in_sizes, int n_in,
                              void* d_out, int out_size, void* d_ws, size_t ws_size,
                              hipStream_t stream)
{
    const float* x   = (const float*)d_in[0];
    const int*   adj = (const int*)  d_in[1];
    const float* W1  = (const float*)d_in[2];
    const float* as1 = (const float*)d_in[3];
    const float* ad1 = (const float*)d_in[4];
    const float* b1  = (const float*)d_in[5];
    const float* W2  = (const float*)d_in[6];
    const float* as2 = (const float*)d_in[7];
    const float* ad2 = (const float*)d_in[8];
    const float* b2  = (const float*)d_in[9];
    float* out = (float*)d_out;

    const size_t szH1b = (size_t)NN * 256 * 2;   // 25.6 MB
    const size_t szT2b = (size_t)NN * 64 * 2;    // 6.4 MB
    const size_t szA4  = (size_t)NN * 4 * 4;     // 0.8 MB
    const size_t szA1  = (size_t)NN * 4;         // 0.2 MB
    const size_t szE   = (size_t)ET * 4;         // 3.4 MB

    char* p = (char*)d_ws;
    ushortT* xb   = (ushortT*)p; p += szH1b;
    ushortT* h1b  = (ushortT*)p; p += szH1b;
    ushortT* a2b  = (ushortT*)p; p += szH1b;
    ushortT* t2b  = (ushortT*)p; p += szT2b;
    ushortT* W1T  = (ushortT*)p; p += 256 * 256 * 2;
    ushortT* W2T  = (ushortT*)p; p += 64 * 256 * 2;
    float* asrc1  = (float*)p; p += szA4;
    float* adst1  = (float*)p; p += szA4;
    float* asrc2  = (float*)p; p += szA1;
    float* adst2  = (float*)p; p += szA1;
    int* esorted  = (int*)p; p += szE;
    int* tmp      = (int*)p; p += szA1;
    int* rowStart = (int*)p; p += szA1;
    int* cursor   = (int*)p; p += szA1;
    int* counts   = (int*)p; p += szA1;
    int* bsum     = (int*)p; p += 4096;

    hipMemsetAsync(counts, 0, szA1, stream);

    const int nb  = (NN + 255) / 256;   // 196
    const int nwb = (NN + 3) / 4;       // 12500

    // castW + castX + hist, one low-resource dispatch
    prep_k<<<256 + XB + EB, 256, 0, stream>>>(W1, W2, x, W1T, W2T, xb, adj, adj + EE, counts);
    scan1_k<<<nb, 256, 0, stream>>>(counts, tmp, bsum);
    scan23_k<<<nb, 256, 0, stream>>>(tmp, bsum, rowStart, cursor);

    // scatter (blocks 0..SCB-1) + layer-1 GEMM (blocks SCB..)
    gemmscatter_k<<<SCB + MT, 256, 0, stream>>>(xb, W1T, as1, ad1, h1b, asrc1, adst1,
                                                adj, adj + EE, cursor, esorted);

    agg1_k<<<nwb, 256, 0, stream>>>(esorted, rowStart, counts, h1b, asrc1, adst1, b1, a2b);
    gemm2_k<<<MT, 256, 0, stream>>>(a2b, W2T, as2, ad2, t2b, asrc2, adst2);
    agg2_k<<<nwb, 256, 0, stream>>>(esorted, rowStart, counts, t2b, asrc2, adst2, b2, out);
}

// Round 8
// 335.180 us; speedup vs baseline: 1.0857x; 1.0348x over previous
//
#include <hip/hip_runtime.h>
#include <cstdint>
#include <cstddef>

// Problem constants
#define NN    50000
#define EE    800000
#define ET    850000   /* EE + NN self-loops */
#define SLOPE 0.2f
#define MT    391      /* (NN+127)/128 gemm row-blocks */
#define EB    3322     /* (ET+255)/256 edge blocks */
#define SCB   416      /* (ET+2047)/2048 scatter blocks (8 edges/thread) */

typedef unsigned short ushortT;
typedef __attribute__((ext_vector_type(8))) short short8;
typedef __attribute__((ext_vector_type(4))) float floatx4;

__device__ __forceinline__ float lrelu(float x){ return x > 0.f ? x : SLOPE * x; }
__device__ __forceinline__ float eluf(float x){ return x > 0.f ? x : __expf(x) - 1.f; }
__device__ __forceinline__ ushortT f2b(float f){ unsigned u = __float_as_uint(f); u += 0x7fff + ((u >> 16) & 1); return (ushortT)(u >> 16); }
__device__ __forceinline__ float   b2f(ushortT b){ return __uint_as_float(((unsigned)b) << 16); }

__device__ __forceinline__ void edge_sd(const int* __restrict__ srcA, const int* __restrict__ dstA,
                                        int e, int& s, int& d)
{
    if (e < EE) { s = srcA[e]; d = dstA[e]; }
    else        { s = e - EE;  d = s; }
}

// ---------------------------------------------------------------------------
// GEMM body: C[M, NT*16](bf16) = A[M,256] @ BT[NT*16,256]^T
// + fused attention-logit epilogue. 128 rows/block, 4 waves.
// A is f32 (inline-cast: reading x once beats a separate cast pass) or bf16.
// ---------------------------------------------------------------------------
template<bool A_F32, int NT, int HEADS>
__device__ __forceinline__ void gemm_body(const void* __restrict__ Aptr,
                                          const ushortT* __restrict__ BT,
                                          const float* __restrict__ attS,
                                          const float* __restrict__ attD,
                                          ushortT* __restrict__ C,
                                          float* __restrict__ asrc,
                                          float* __restrict__ adst,
                                          int M, int bId,
                                          ushortT* As, ushortT* Bs)
{
    constexpr int NCOL = NT * 16;
    const int tid  = threadIdx.x;
    const int wave = tid >> 6;
    const int lane = tid & 63;
    const int m16  = lane & 15;
    const int quad = lane >> 4;
    const int row0 = bId * 128;
    const int arow = tid >> 1;
    const int acol = (tid & 1) << 4;
    const long arowG = min(row0 + arow, M - 1);

    floatx4 acc[2][NT];
    #pragma unroll
    for (int i = 0; i < 2; ++i)
        #pragma unroll
        for (int j = 0; j < NT; ++j) acc[i][j] = (floatx4){0.f, 0.f, 0.f, 0.f};

    for (int k0 = 0; k0 < 256; k0 += 32) {
        ushortT a16[16];
        if (A_F32) {
            const float* A = (const float*)Aptr;
            #pragma unroll
            for (int q = 0; q < 4; ++q) {
                float4 f = *(const float4*)(A + arowG * 256 + k0 + acol + q * 4);
                a16[q*4+0] = f2b(f.x); a16[q*4+1] = f2b(f.y);
                a16[q*4+2] = f2b(f.z); a16[q*4+3] = f2b(f.w);
            }
        } else {
            const ushortT* A = (const ushortT*)Aptr;
            *(uint4*)(a16)     = *(const uint4*)(A + arowG * 256 + k0 + acol);
            *(uint4*)(a16 + 8) = *(const uint4*)(A + arowG * 256 + k0 + acol + 8);
        }
        uint4 bst[(NT == 16) ? 4 : 1];
        if (NT == 16) {
            const ushortT* bp = BT + (size_t)tid * 256 + k0;
            #pragma unroll
            for (int q = 0; q < 4; ++q) bst[q] = *(const uint4*)(bp + q * 8);
        } else {
            int brow = tid >> 2, bcol = (tid & 3) << 3;
            bst[0] = *(const uint4*)(BT + (size_t)brow * 256 + k0 + bcol);
        }

        __syncthreads();
        *(uint4*)(&As[arow * 40 + acol])     = *(uint4*)(a16);
        *(uint4*)(&As[arow * 40 + acol + 8]) = *(uint4*)(a16 + 8);
        if (NT == 16) {
            #pragma unroll
            for (int q = 0; q < 4; ++q) *(uint4*)(&Bs[tid * 40 + q * 8]) = bst[q];
        } else {
            int brow = tid >> 2, bcol = (tid & 3) << 3;
            *(uint4*)(&Bs[brow * 40 + bcol]) = bst[0];
        }
        __syncthreads();

        short8 af0 = *(const short8*)(&As[(wave * 32 + m16) * 40 + quad * 8]);
        short8 af1 = *(const short8*)(&As[(wave * 32 + 16 + m16) * 40 + quad * 8]);
        #pragma unroll
        for (int j = 0; j < NT; ++j) {
            short8 bf = *(const short8*)(&Bs[(j * 16 + m16) * 40 + quad * 8]);
            acc[0][j] = __builtin_amdgcn_mfma_f32_16x16x32_bf16(af0, bf, acc[0][j], 0, 0, 0);
            acc[1][j] = __builtin_amdgcn_mfma_f32_16x16x32_bf16(af1, bf, acc[1][j], 0, 0, 0);
        }
    }

    float attSv[NT], attDv[NT];
    #pragma unroll
    for (int j = 0; j < NT; ++j) {
        attSv[j] = attS[j * 16 + m16];
        attDv[j] = attD[j * 16 + m16];
    }

    #pragma unroll
    for (int i = 0; i < 2; ++i) {
        #pragma unroll
        for (int r = 0; r < 4; ++r) {
            int row = row0 + wave * 32 + i * 16 + quad * 4 + r;
            bool ok = row < M;
            if (ok) {
                #pragma unroll
                for (int j = 0; j < NT; ++j)
                    C[(size_t)row * NCOL + j * 16 + m16] = f2b(acc[i][j][r]);
            }
            float ds[HEADS], dd[HEADS];
            #pragma unroll
            for (int h = 0; h < HEADS; ++h) {
                float s = 0.f, d2 = 0.f;
                #pragma unroll
                for (int jj = 0; jj < 4; ++jj) {
                    int j = h * 4 + jj;
                    s  += acc[i][j][r] * attSv[j];
                    d2 += acc[i][j][r] * attDv[j];
                }
                #pragma unroll
                for (int off = 1; off < 16; off <<= 1) {
                    s  += __shfl_xor(s, off);
                    d2 += __shfl_xor(d2, off);
                }
                ds[h] = s; dd[h] = d2;
            }
            if (ok && m16 == 0) {
                if (HEADS == 4) {
                    *(float4*)(asrc + (size_t)row * 4) = make_float4(ds[0], ds[1], ds[2], ds[3]);
                    *(float4*)(adst + (size_t)row * 4) = make_float4(dd[0], dd[1], dd[2], dd[3]);
                } else {
                    asrc[row] = ds[0];
                    adst[row] = dd[0];
                }
            }
        }
    }
}

// ---------------------------------------------------------------------------
// Fused prep: blocks [0,256) cast weights; [256,..) histogram edge dst.
// Both parts low-VGPR/no-LDS -> safe heterogeneous fusion.
// ---------------------------------------------------------------------------
__global__ __launch_bounds__(256) void prep_k(const float* __restrict__ W1, const float* __restrict__ W2,
                                              ushortT* __restrict__ W1T, ushortT* __restrict__ W2T,
                                              const int* __restrict__ srcA, const int* __restrict__ dstA,
                                              int* __restrict__ counts)
{
    int t = threadIdx.x;
    int b = blockIdx.x;
    if (b < 256) {
        W1T[t * 256 + b] = f2b(W1[b * 256 + t]);
        if (t < 64) W2T[t * 256 + b] = f2b(W2[b * 64 + t]);
    } else {
        int e = (b - 256) * 256 + t;
        if (e >= ET) return;
        int s, d; edge_sd(srcA, dstA, e, s, d);
        atomicAdd(counts + d, 1);
    }
}

// ---------------------------------------------------------------------------
// scan1: per-256-block inclusive scan -> exclusive tmp + block sums
// ---------------------------------------------------------------------------
__global__ __launch_bounds__(256) void scan1_k(const int* __restrict__ counts,
                                               int* __restrict__ tmp, int* __restrict__ bsum)
{
    __shared__ int sm[256];
    int i = blockIdx.x * 256 + threadIdx.x;
    int v = (i < NN) ? counts[i] : 0;
    sm[threadIdx.x] = v;
    __syncthreads();
    #pragma unroll
    for (int off = 1; off < 256; off <<= 1) {
        int t = (threadIdx.x >= off) ? sm[threadIdx.x - off] : 0;
        __syncthreads();
        sm[threadIdx.x] += t;
        __syncthreads();
    }
    if (i < NN) tmp[i] = sm[threadIdx.x] - v;
    if (threadIdx.x == 255) bsum[blockIdx.x] = sm[255];
}

// scan23: block b adds sum(bsum[0..b)) to tmp -> rowStart, cursor. (196 <= 256)
__global__ __launch_bounds__(256) void scan23_k(const int* __restrict__ tmp, const int* __restrict__ bsum,
                                                int* __restrict__ rowStart, int* __restrict__ cursor)
{
    __shared__ int sm[4];
    int t = threadIdx.x;
    int v = (t < blockIdx.x) ? bsum[t] : 0;
    #pragma unroll
    for (int off = 32; off; off >>= 1) v += __shfl_xor(v, off);
    if ((t & 63) == 0) sm[t >> 6] = v;
    __syncthreads();
    int base = sm[0] + sm[1] + sm[2] + sm[3];
    int i = blockIdx.x * 256 + t;
    if (i < NN) {
        int r = tmp[i] + base;
        rowStart[i] = r;
        cursor[i]   = r;
    }
}

// ---------------------------------------------------------------------------
// Fused: blocks [0,MT) layer-1 GEMM (+alpha epilogue); blocks [MT, MT+SCB)
// scatter edges, 8 independent edges/thread (8 atomics in flight to amortize
// the gemm-sized resource bill these blocks inherit). GEMM FIRST: scatter
// blocks then trickle into freed slots behind resident gemm blocks
// (R4 vs R6 A/B: scatter-first cost +21us).
// ---------------------------------------------------------------------------
__global__ __launch_bounds__(256) void gemmscatter_k(const float* __restrict__ x,
                                                     const ushortT* __restrict__ W1T,
                                                     const float* __restrict__ attS,
                                                     const float* __restrict__ attD,
                                                     ushortT* __restrict__ h1b,
                                                     float* __restrict__ asrc,
                                                     float* __restrict__ adst,
                                                     const int* __restrict__ srcA,
                                                     const int* __restrict__ dstA,
                                                     int* __restrict__ cursor,
                                                     int* __restrict__ esorted)
{
    __shared__ ushortT As[128 * 40];
    __shared__ ushortT Bs[256 * 40];
    if (blockIdx.x < MT) {
        gemm_body<true, 16, 4>(x, W1T, attS, attD, h1b, asrc, adst, NN, blockIdx.x, As, Bs);
    } else {
        int base = (blockIdx.x - MT) * 2048 + threadIdx.x;
        #pragma unroll
        for (int k = 0; k < 8; ++k) {
            int e = base + k * 256;
            if (e < ET) {
                int s, d; edge_sd(srcA, dstA, e, s, d);
                int pos = atomicAdd(cursor + d, 1);
                esorted[pos] = s;
            }
        }
    }
}

// Layer-2 GEMM standalone
__global__ __launch_bounds__(256) void gemm2_k(const ushortT* __restrict__ a2b,
                                               const ushortT* __restrict__ W2T,
                                               const float* __restrict__ attS,
                                               const float* __restrict__ attD,
                                               ushortT* __restrict__ t2b,
                                               float* __restrict__ asrc,
                                               float* __restrict__ adst)
{
    __shared__ ushortT As[128 * 40];
    __shared__ ushortT Bs[64 * 40];
    gemm_body<false, 4, 1>(a2b, W2T, attS, attD, t2b, asrc, adst, NN, blockIdx.x, As, Bs);
}

// ---------------------------------------------------------------------------
// agg1: chunked pass. Lane=edge computes p (4 heads) once into wave-local LDS;
// all lanes gather h1b rows weighted by LDS-broadcast p. Phase B unroll 8.
// ---------------------------------------------------------------------------
__global__ __launch_bounds__(256) void agg1_k(const int* __restrict__ esorted,
                                              const int* __restrict__ rowStart,
                                              const int* __restrict__ counts,
                                              const ushortT* __restrict__ h1b,
                                              const float* __restrict__ asrc,
                                              const float* __restrict__ adst,
                                              const float* __restrict__ b1,
                                              ushortT* __restrict__ a2b)
{
    __shared__ float pbuf[4][64][4];
    __shared__ int   sbuf[4][64];
    int w = threadIdx.x >> 6;
    int lane = threadIdx.x & 63;
    int n = blockIdx.x * 4 + w;
    if (n >= NN) return;
    int start = rowStart[n], deg = counts[n];
    float4 adv = *(const float4*)(adst + (size_t)n * 4);
    int h = lane >> 4;
    int c4 = lane * 4;

    float4 ssv = make_float4(0.f, 0.f, 0.f, 0.f);
    float4 ac0 = make_float4(0.f,0.f,0.f,0.f);
    float4 ac1 = make_float4(0.f,0.f,0.f,0.f);
    float4 ac2 = make_float4(0.f,0.f,0.f,0.f);
    float4 ac3 = make_float4(0.f,0.f,0.f,0.f);

    for (int base = 0; base < deg; base += 64) {
        int cl = min(64, deg - base);
        int i = base + lane;
        if (i < deg) {
            int s = esorted[start + i];
            float4 a = *(const float4*)(asrc + (size_t)s * 4);
            float4 pv;
            pv.x = __expf(lrelu(a.x + adv.x));
            pv.y = __expf(lrelu(a.y + adv.y));
            pv.z = __expf(lrelu(a.z + adv.z));
            pv.w = __expf(lrelu(a.w + adv.w));
            ssv.x += pv.x; ssv.y += pv.y; ssv.z += pv.z; ssv.w += pv.w;
            *(float4*)(&pbuf[w][lane][0]) = pv;
            sbuf[w][lane] = s;
        }
        __builtin_amdgcn_wave_barrier();   // intra-wave LDS write->read ordering
        int j = 0;
        for (; j + 7 < cl; j += 8) {
            float4 hv[8]; float pp[8];
            #pragma unroll
            for (int q = 0; q < 8; ++q) {
                int sq = sbuf[w][j + q];
                pp[q] = pbuf[w][j + q][h];
                ushort4 hq = *(const ushort4*)(h1b + (size_t)sq * 256 + c4);
                hv[q] = make_float4(b2f(hq.x), b2f(hq.y), b2f(hq.z), b2f(hq.w));
            }
            #pragma unroll
            for (int q = 0; q < 8; ++q) {
                float4* ac = (q & 3) == 0 ? &ac0 : (q & 3) == 1 ? &ac1 : (q & 3) == 2 ? &ac2 : &ac3;
                ac->x += hv[q].x * pp[q]; ac->y += hv[q].y * pp[q];
                ac->z += hv[q].z * pp[q]; ac->w += hv[q].w * pp[q];
            }
        }
        for (; j < cl; ++j) {
            int s0 = sbuf[w][j];
            float p0 = pbuf[w][j][h];
            ushort4 h0 = *(const ushort4*)(h1b + (size_t)s0 * 256 + c4);
            ac0.x += b2f(h0.x) * p0; ac0.y += b2f(h0.y) * p0; ac0.z += b2f(h0.z) * p0; ac0.w += b2f(h0.w) * p0;
        }
        __builtin_amdgcn_wave_barrier();   // reads done before next chunk's writes
    }

    #pragma unroll
    for (int off = 1; off < 64; off <<= 1) {
        ssv.x += __shfl_xor(ssv.x, off); ssv.y += __shfl_xor(ssv.y, off);
        ssv.z += __shfl_xor(ssv.z, off); ssv.w += __shfl_xor(ssv.w, off);
    }
    float ssh = (h < 2) ? (h == 0 ? ssv.x : ssv.y) : (h == 2 ? ssv.z : ssv.w);
    float rdh = 1.f / ssh;

    float4 bv = *(const float4*)(b1 + c4);
    ushort4 o;
    o.x = f2b(eluf((ac0.x + ac1.x + ac2.x + ac3.x) * rdh + bv.x));
    o.y = f2b(eluf((ac0.y + ac1.y + ac2.y + ac3.y) * rdh + bv.y));
    o.z = f2b(eluf((ac0.z + ac1.z + ac2.z + ac3.z) * rdh + bv.z));
    o.w = f2b(eluf((ac0.w + ac1.w + ac2.w + ac3.w) * rdh + bv.w));
    *(ushort4*)(a2b + (size_t)n * 256 + c4) = o;
}

// ---------------------------------------------------------------------------
// agg2: same chunked-LDS structure, 1 head + bias + log_softmax. Unroll 8.
// ---------------------------------------------------------------------------
__global__ __launch_bounds__(256) void agg2_k(const int* __restrict__ esorted,
                                              const int* __restrict__ rowStart,
                                              const int* __restrict__ counts,
                                              const ushortT* __restrict__ t2b,
                                              const float* __restrict__ asrc,
                                              const float* __restrict__ adst,
                                              const float* __restrict__ b2,
                                              float* __restrict__ out)
{
    __shared__ float pbuf[4][64];
    __shared__ int   sbuf[4][64];
    int w = threadIdx.x >> 6;
    int lane = threadIdx.x & 63;
    int n = blockIdx.x * 4 + w;
    if (n >= NN) return;
    int start = rowStart[n], deg = counts[n];
    float adv = adst[n];

    float ss = 0.f;
    float a0 = 0.f, a1 = 0.f, a2 = 0.f, a3 = 0.f;

    for (int base = 0; base < deg; base += 64) {
        int cl = min(64, deg - base);
        int i = base + lane;
        if (i < deg) {
            int s = esorted[start + i];
            float p = __expf(lrelu(asrc[s] + adv));
            ss += p;
            pbuf[w][lane] = p;
            sbuf[w][lane] = s;
        }
        __builtin_amdgcn_wave_barrier();
        int j = 0;
        for (; j + 7 < cl; j += 8) {
            float tv[8]; float pp[8];
            #pragma unroll
            for (int q = 0; q < 8; ++q) {
                int sq = sbuf[w][j + q];
                pp[q] = pbuf[w][j + q];
                tv[q] = b2f(t2b[(size_t)sq * 64 + lane]);
            }
            #pragma unroll
            for (int q = 0; q < 8; ++q) {
                float* ac = (q & 3) == 0 ? &a0 : (q & 3) == 1 ? &a1 : (q & 3) == 2 ? &a2 : &a3;
                *ac += tv[q] * pp[q];
            }
        }
        for (; j < cl; ++j) {
            a0 += b2f(t2b[(size_t)sbuf[w][j] * 64 + lane]) * pbuf[w][j];
        }
        __builtin_amdgcn_wave_barrier();
    }

    #pragma unroll
    for (int off = 1; off < 64; off <<= 1) ss += __shfl_xor(ss, off);
    float v = (a0 + a1 + a2 + a3) / ss + b2[lane];

    float m2 = v;
    #pragma unroll
    for (int off = 32; off; off >>= 1) m2 = fmaxf(m2, __shfl_xor(m2, off));
    float ex = __expf(v - m2);
    float sm = ex;
    #pragma unroll
    for (int off = 32; off; off >>= 1) sm += __shfl_xor(sm, off);
    out[(size_t)n * 64 + lane] = v - m2 - __logf(sm);
}

// ---------------------------------------------------------------------------
extern "C" void kernel_launch(void* const* d_in, const int* in_sizes, int n_in,
                              void* d_out, int out_size, void* d_ws, size_t ws_size,
                              hipStream_t stream)
{
    const float* x   = (const float*)d_in[0];
    const int*   adj = (const int*)  d_in[1];
    const float* W1  = (const float*)d_in[2];
    const float* as1 = (const float*)d_in[3];
    const float* ad1 = (const float*)d_in[4];
    const float* b1  = (const float*)d_in[5];
    const float* W2  = (const float*)d_in[6];
    const float* as2 = (const float*)d_in[7];
    const float* ad2 = (const float*)d_in[8];
    const float* b2  = (const float*)d_in[9];
    float* out = (float*)d_out;

    const size_t szH1b = (size_t)NN * 256 * 2;   // 25.6 MB
    const size_t szT2b = (size_t)NN * 64 * 2;    // 6.4 MB
    const size_t szA4  = (size_t)NN * 4 * 4;     // 0.8 MB
    const size_t szA1  = (size_t)NN * 4;         // 0.2 MB
    const size_t szE   = (size_t)ET * 4;         // 3.4 MB

    char* p = (char*)d_ws;
    ushortT* h1b  = (ushortT*)p; p += szH1b;
    ushortT* a2b  = (ushortT*)p; p += szH1b;
    ushortT* t2b  = (ushortT*)p; p += szT2b;
    ushortT* W1T  = (ushortT*)p; p += 256 * 256 * 2;
    ushortT* W2T  = (ushortT*)p; p += 64 * 256 * 2;
    float* asrc1  = (float*)p; p += szA4;
    float* adst1  = (float*)p; p += szA4;
    float* asrc2  = (float*)p; p += szA1;
    float* adst2  = (float*)p; p += szA1;
    int* esorted  = (int*)p; p += szE;
    int* tmp      = (int*)p; p += szA1;
    int* rowStart = (int*)p; p += szA1;
    int* cursor   = (int*)p; p += szA1;
    int* counts   = (int*)p; p += szA1;
    int* bsum     = (int*)p; p += 4096;

    hipMemsetAsync(counts, 0, szA1, stream);

    const int nb  = (NN + 255) / 256;   // 196
    const int nwb = (NN + 3) / 4;       // 12500

    // castW (blocks 0..255) + hist (blocks 256..)
    prep_k<<<256 + EB, 256, 0, stream>>>(W1, W2, W1T, W2T, adj, adj + EE, counts);
    scan1_k<<<nb, 256, 0, stream>>>(counts, tmp, bsum);
    scan23_k<<<nb, 256, 0, stream>>>(tmp, bsum, rowStart, cursor);

    // gemm1 (blocks 0..MT-1, f32 A inline-cast) + scatter (blocks MT.., 8 edges/thread)
    gemmscatter_k<<<MT + SCB, 256, 0, stream>>>(x, W1T, as1, ad1, h1b, asrc1, adst1,
                                                adj, adj + EE, cursor, esorted);

    agg1_k<<<nwb, 256, 0, stream>>>(esorted, rowStart, counts, h1b, asrc1, adst1, b1, a2b);
    gemm2_k<<<MT, 256, 0, stream>>>(a2b, W2T, as2, ad2, t2b, asrc2, adst2);
    agg2_k<<<nwb, 256, 0, stream>>>(esorted, rowStart, counts, t2b, asrc2, adst2, b2, out);
}